// Round 10
// baseline (203.143 us; speedup 1.0000x reference)
//
#include <hip/hip_runtime.h>
#include <cstdint>

#define BB 16
#define DD 64
#define LL 2048
#define NQ (BB*LL)          // 32768 queries
#define KK 8192             // codebook entries
#define VQ_SIZE (BB*DD*LL)  // 2097152 floats
#define CHUNK 256
#define NCH (KK/CHUNK)      // 32 chunks
#define QSL 512             // query slices per chunk in vq_exact
#define QPS (NQ/QSL)        // 64 queries per slice (exactly 1 bitmap word)
#define MARGIN 0.75f        // > worst-case 2*eps_bf16 (~0.60) + slack

typedef __attribute__((ext_vector_type(8))) short short8;
typedef __attribute__((ext_vector_type(4))) float f32x4;
typedef unsigned long long u64;

// d_out region reuse:
//   [0, 4MB)  xb bf16 (screen input)      } both dead after vq_cand ->
//   [4, 8MB)  cmaxT [NCH][NQ] f32         }   xf f32 [NQ][64] (8 MB exactly)
//   [8MB, +128KB) indices region: qmask[NCH][NQ/64] u64 (exactly 128 KB),
//                 overwritten with float indices by vq_gather at the end.
// d_ws: nh2[KK] f32 (32KB) + keys[NQ] u64 (256KB) = 288KB (proven available)

static __device__ inline short f2bf(float f) {   // RNE f32 -> bf16
    uint32_t u = __float_as_uint(f);
    uint32_t r = (u + 0x7FFFu + ((u >> 16) & 1u)) >> 16;
    return (short)r;
}

// DPP-based wave64 min-reduce step: v = min(v, lanes-shifted v). Pure VALU.
#define FMIN_DPP(v, ctrl)                                                     \
    do {                                                                      \
        int _vi = __float_as_int(v);                                          \
        int _sh = __builtin_amdgcn_update_dpp(_vi, _vi, (ctrl), 0xf, 0xf, false); \
        (v) = fminf((v), __int_as_float(_sh));                                \
    } while (0)

// ---- prep: z_e [B][D][L] f32 -> X_bf16 [B*L][D], LDS-transposed ----
__global__ __launch_bounds__(256) void prep_x(const float* __restrict__ ze,
                                              short* __restrict__ xb) {
    __shared__ float t[64][65];
    const int b = blockIdx.x;
    const int l0 = blockIdx.y * 64;
    const int tid = threadIdx.x;
    #pragma unroll
    for (int it = 0; it < 4; ++it) {
        int id = it * 256 + tid;
        int d = id >> 4;
        int lw = (id & 15) * 4;
        const float4 v = *(const float4*)(ze + ((size_t)b * DD + d) * LL + l0 + lw);
        t[d][lw + 0] = v.x; t[d][lw + 1] = v.y; t[d][lw + 2] = v.z; t[d][lw + 3] = v.w;
    }
    __syncthreads();
    #pragma unroll
    for (int it = 0; it < 2; ++it) {
        int id = it * 256 + tid;
        int lr = id >> 3;
        int u = id & 7;
        short8 o;
        #pragma unroll
        for (int e = 0; e < 8; ++e) o[e] = f2bf(t[u * 8 + e][lr]);
        *(short8*)(xb + (size_t)(b * LL + l0 + lr) * DD + u * 8) = o;
    }
}

// ---- prep: z_e -> xf f32 [B*L][D] (for vector-load exact pass) ----
__global__ __launch_bounds__(256) void prep_xf(const float* __restrict__ ze,
                                               float* __restrict__ xf) {
    __shared__ float t[64][65];
    const int b = blockIdx.x;
    const int l0 = blockIdx.y * 64;
    const int tid = threadIdx.x;
    #pragma unroll
    for (int it = 0; it < 4; ++it) {
        int id = it * 256 + tid;
        int d = id >> 4;
        int lw = (id & 15) * 4;
        const float4 v = *(const float4*)(ze + ((size_t)b * DD + d) * LL + l0 + lw);
        t[d][lw + 0] = v.x; t[d][lw + 1] = v.y; t[d][lw + 2] = v.z; t[d][lw + 3] = v.w;
    }
    __syncthreads();
    #pragma unroll
    for (int it = 0; it < 4; ++it) {
        int id = it * 256 + tid;        // row*16 + u
        int row = id >> 4;
        int u = id & 15;
        float4 o = make_float4(t[4 * u + 0][row], t[4 * u + 1][row],
                               t[4 * u + 2][row], t[4 * u + 3][row]);
        *(float4*)(xf + (size_t)(b * LL + l0 + row) * DD + u * 4) = o;
    }
}

// ---- prep: nh2[k] = -0.5*||c_k||^2 ----
__global__ __launch_bounds__(256) void prep_nh2(const float* __restrict__ cbf,
                                                float* __restrict__ nh2) {
    int k = blockIdx.x * 256 + threadIdx.x;
    const float4* c4 = (const float4*)(cbf + (size_t)k * DD);
    float s = 0.f;
    #pragma unroll
    for (int i = 0; i < DD / 4; ++i) {
        float4 v = c4[i];
        s += v.x * v.x + v.y * v.y + v.z * v.z + v.w * v.w;
    }
    nh2[k] = -0.5f * s;
}

// ---- Phase A: bf16 MFMA screen -> cmaxT[ch][q] = max_k s(q,k) over chunk ----
__global__ __launch_bounds__(256) void vq_screen(const float* __restrict__ cbf,
                                                 const float* __restrict__ nh2,
                                                 const short* __restrict__ xb,
                                                 float* __restrict__ cmaxT) {
    __shared__ short cbt[CHUNK * 64];   // 32KB, XOR-swizzled bf16 chunk
    __shared__ float sh2[CHUNK];
    const int tid = threadIdx.x;
    const int lane = tid & 63;
    const int wid = tid >> 6;
    const int kbase = blockIdx.y * CHUNK;
    const int qbase = blockIdx.x * 256 + wid * 64;
    const int r16 = lane & 15, g = lane >> 4;

    #pragma unroll
    for (int it = 0; it < 8; ++it) {
        int id = it * 256 + tid;
        int row = id >> 3;
        int u = id & 7;
        const float4 lo = *(const float4*)(cbf + (size_t)(kbase + row) * 64 + u * 8);
        const float4 hi = *(const float4*)(cbf + (size_t)(kbase + row) * 64 + u * 8 + 4);
        short8 o;
        o[0] = f2bf(lo.x); o[1] = f2bf(lo.y); o[2] = f2bf(lo.z); o[3] = f2bf(lo.w);
        o[4] = f2bf(hi.x); o[5] = f2bf(hi.y); o[6] = f2bf(hi.z); o[7] = f2bf(hi.w);
        *(short8*)(&cbt[row * 64 + ((u ^ (row & 7)) * 8)]) = o;
    }
    sh2[tid] = nh2[kbase + tid];
    __syncthreads();

    short8 a[4][2];
    #pragma unroll
    for (int t = 0; t < 4; ++t)
        #pragma unroll
        for (int ks = 0; ks < 2; ++ks)
            a[t][ks] = *(const short8*)(xb + (size_t)(qbase + t * 16 + r16) * 64 + ks * 32 + g * 8);

    float rm[4][4];
    #pragma unroll
    for (int t = 0; t < 4; ++t)
        #pragma unroll
        for (int j = 0; j < 4; ++j) rm[t][j] = -3.4e38f;

    for (int cs = 0; cs < CHUNK / 16; ++cs) {
        const int rowb = cs * 16 + r16;
        const float nh = sh2[rowb];
        const f32x4 ci = {nh, nh, nh, nh};
        const short8 b0 = *(const short8*)(&cbt[rowb * 64 + ((g ^ (rowb & 7)) * 8)]);
        const short8 b1 = *(const short8*)(&cbt[rowb * 64 + (((g + 4) ^ (rowb & 7)) * 8)]);
        #pragma unroll
        for (int t = 0; t < 4; ++t) {
            f32x4 acc = __builtin_amdgcn_mfma_f32_16x16x32_bf16(a[t][0], b0, ci, 0, 0, 0);
            acc = __builtin_amdgcn_mfma_f32_16x16x32_bf16(a[t][1], b1, acc, 0, 0, 0);
            rm[t][0] = fmaxf(rm[t][0], acc[0]);
            rm[t][1] = fmaxf(rm[t][1], acc[1]);
            rm[t][2] = fmaxf(rm[t][2], acc[2]);
            rm[t][3] = fmaxf(rm[t][3], acc[3]);
        }
    }

    #pragma unroll
    for (int s = 1; s < 16; s <<= 1)
        #pragma unroll
        for (int t = 0; t < 4; ++t)
            #pragma unroll
            for (int j = 0; j < 4; ++j)
                rm[t][j] = fmaxf(rm[t][j], __shfl_xor(rm[t][j], s));

    if (r16 == 0) {   // transposed write: cmaxT[ch][q]
        #pragma unroll
        for (int t = 0; t < 4; ++t)
            #pragma unroll
            for (int j = 0; j < 4; ++j)
                cmaxT[(size_t)blockIdx.y * NQ + (qbase + t * 16 + g * 4 + j)] = rm[t][j];
    }
}

// ---- Phase B1: candidate bitmap via ballot (atomic-free, deterministic) ----
__global__ __launch_bounds__(256) void vq_cand(const float* __restrict__ cmaxT,
                                               u64* __restrict__ qmask,
                                               u64* __restrict__ keys) {
    const int tid = threadIdx.x;
    const int lane = tid & 63;
    const int q = blockIdx.x * 256 + tid;
    const int qword = q >> 6;   // wave-uniform
    float v[NCH];
    float m = -3.4e38f;
    #pragma unroll
    for (int j = 0; j < NCH; ++j) {
        v[j] = cmaxT[(size_t)j * NQ + q];
        m = fmaxf(m, v[j]);
    }
    keys[q] = ~0ULL;
    const float thr = m - MARGIN;
    #pragma unroll
    for (int j = 0; j < NCH; ++j) {
        u64 mm = __ballot(v[j] >= thr);
        if (lane == 0) qmask[(size_t)j * (NQ / 64) + qword] = mm;
    }
}

// ---- Phase B2: exact fp32 pass. lane=code; single bitmap word per block;
//      DPP min-reduce (pure VALU, no LDS-pipe shuffles) ----
__global__ __launch_bounds__(256) void vq_exact(const float* __restrict__ xf,
                                                const float* __restrict__ cbf,
                                                const float* __restrict__ nh2,
                                                const u64* __restrict__ qmask,
                                                u64* __restrict__ keys) {
    const int ch = blockIdx.x;
    const int slice = blockIdx.y;                 // 0..QSL-1
    const int lane = threadIdx.x & 63;
    const int wid = threadIdx.x >> 6;
    const int kb = ch * CHUNK + wid * 64;
    const int k = kb + lane;

    u64 x = qmask[(size_t)ch * (NQ / 64) + slice];
    uint32_t lo = __builtin_amdgcn_readfirstlane((uint32_t)x);
    uint32_t hi = __builtin_amdgcn_readfirstlane((uint32_t)(x >> 32));
    u64 sw = ((u64)hi << 32) | lo;                // SALU-resident
    if (!sw) return;                              // skip code load entirely

    float cdv[64];                                // this lane's code row
    #pragma unroll
    for (int i = 0; i < 16; ++i)
        *(float4*)&cdv[4 * i] = *(const float4*)(cbf + (size_t)k * DD + 4 * i);
    const float nh2k = nh2[k];

    while (sw) {
        const int bit = __ffsll((long long)sw) - 1;
        sw &= sw - 1;
        const int q = slice * QPS + bit;
        const float4* xr4 = (const float4*)(xf + (size_t)q * DD);
        float4 xv[16];                            // 16 independent loads in flight
        #pragma unroll
        for (int i = 0; i < 16; ++i) xv[i] = xr4[i];

        float a0 = 0.f, a1 = 0.f, a2 = 0.f, a3 = 0.f;
        #pragma unroll
        for (int i = 0; i < 16; ++i) {            // 4 independent fma chains
            a0 = fmaf(xv[i].x, cdv[4 * i + 0], a0);
            a1 = fmaf(xv[i].y, cdv[4 * i + 1], a1);
            a2 = fmaf(xv[i].z, cdv[4 * i + 2], a2);
            a3 = fmaf(xv[i].w, cdv[4 * i + 3], a3);
        }
        float val = -(((a0 + a1) + (a2 + a3)) + nh2k);

        // wave64 min via DPP (rocPRIM pattern): row_shr 1,2,4,8 -> bcast15 -> bcast31
        float mn = val;
        FMIN_DPP(mn, 0x111);   // row_shr:1
        FMIN_DPP(mn, 0x112);   // row_shr:2
        FMIN_DPP(mn, 0x114);   // row_shr:4
        FMIN_DPP(mn, 0x118);   // row_shr:8
        FMIN_DPP(mn, 0x142);   // row_bcast:15
        FMIN_DPP(mn, 0x143);   // row_bcast:31
        const float mnall = __uint_as_float(
            __builtin_amdgcn_readlane(__float_as_uint(mn), 63));

        u64 mk = __ballot(val == mnall);          // lane order = code order
        int srcl = __ffsll((long long)mk) - 1;    // lowest index on ties
        uint32_t uu = __float_as_uint(mnall);
        uint32_t ub = ((int)uu < 0) ? ~uu : (uu | 0x80000000u);
        u64 key = ((u64)ub << 32) | (unsigned)(kb + srcl);
        if (lane == 0) atomicMin(&keys[q], key);
    }
}

// ---- final: v_q gather + index write (d==0 threads emit indices) ----
__global__ __launch_bounds__(256) void vq_gather(const float* __restrict__ cb,
                                                 const u64* __restrict__ keys,
                                                 float* __restrict__ vq,
                                                 float* __restrict__ oidx) {
    int t = blockIdx.x * 256 + threadIdx.x;
    int l = t & (LL - 1);
    int bd = t >> 11;
    int d = bd & 63;
    int b = bd >> 6;
    int idx = (int)(unsigned)(keys[b * LL + l] & 0x1FFFu);
    vq[t] = cb[idx * DD + d];
    if (d == 0) oidx[b * LL + l] = (float)idx;
}

extern "C" void kernel_launch(void* const* d_in, const int* in_sizes, int n_in,
                              void* d_out, int out_size, void* d_ws, size_t ws_size,
                              hipStream_t stream) {
    const float* ze = (const float*)d_in[0];
    const float* cb = (const float*)d_in[1];
    float* out = (float*)d_out;

    short* xb = (short*)d_out;                                    // [0,4MB)
    float* cmaxT = (float*)((char*)d_out + (size_t)NQ * DD * 2);  // [4,8MB)
    float* xf = (float*)d_out;                                    // [0,8MB) after cand
    u64* qmask = (u64*)(out + VQ_SIZE);                           // 128KB indices region
    float* nh2 = (float*)d_ws;                                    // 32KB
    u64* keys = (u64*)((char*)d_ws + (size_t)KK * 4);             // 256KB
    float* oidx = out + VQ_SIZE;

    dim3 gx(BB, LL / 64);
    prep_x<<<gx, 256, 0, stream>>>(ze, xb);
    prep_nh2<<<KK / 256, 256, 0, stream>>>(cb, nh2);

    dim3 gs(NQ / 256, NCH);
    vq_screen<<<gs, 256, 0, stream>>>(cb, nh2, xb, cmaxT);

    vq_cand<<<NQ / 256, 256, 0, stream>>>(cmaxT, qmask, keys);

    prep_xf<<<gx, 256, 0, stream>>>(ze, xf);   // overwrites xb+cmaxT (both dead)

    dim3 ge(NCH, QSL);
    vq_exact<<<ge, 256, 0, stream>>>(xf, cb, nh2, qmask, keys);

    vq_gather<<<VQ_SIZE / 256, 256, 0, stream>>>(cb, keys, out, oidx);
}

// Round 11
// 192.931 us; speedup vs baseline: 1.0529x; 1.0529x over previous
//
#include <hip/hip_runtime.h>
#include <hip/hip_fp16.h>
#include <cstdint>

#define BB 16
#define DD 64
#define LL 2048
#define NQ (BB*LL)          // 32768 queries
#define KK 8192             // codebook entries
#define VQ_SIZE (BB*DD*LL)  // 2097152 floats
#define CHUNK 256           // screen block's code tile
#define NCH (KK/CHUNK)      // 32 screen chunks
#define NG (KK/128)         // 64 cmax groups (128 codes each)
#define NHG (KK/64)         // 128 exact half-groups (64 codes = 1 wave)
#define ESL 128             // exact q-slices
#define EQS (NQ/ESL)        // 256 queries per exact slice
#define MARGIN 0.95f        // bf16 screen worst (~0.60) + 2x fp16 storage (0.25) + slack

typedef __attribute__((ext_vector_type(8))) short short8;
typedef __attribute__((ext_vector_type(4))) float f32x4;
typedef unsigned long long u64;

// d_out layout:
//   [0, 4MB)   xb: X_bf16 [NQ][64] (screen A operand; dead after screen)
//   [4, 8MB)   cmaxG: fp16 [NG][NQ] group maxes (live until exact done)
//   [8MB,+64KB) thr: fp16 [NQ] thresholds (indices region; overwritten by oidx)
// d_ws: nh2[KK] f32 (32KB) + keys[NQ] u64 (256KB) = 288KB (proven available)

static __device__ inline short f2bf(float f) {   // RNE f32 -> bf16
    uint32_t u = __float_as_uint(f);
    uint32_t r = (u + 0x7FFFu + ((u >> 16) & 1u)) >> 16;
    return (short)r;
}

// DPP-based wave64 min-reduce step (pure VALU; verified correct in round 10)
#define FMIN_DPP(v, ctrl)                                                     \
    do {                                                                      \
        int _vi = __float_as_int(v);                                          \
        int _sh = __builtin_amdgcn_update_dpp(_vi, _vi, (ctrl), 0xf, 0xf, false); \
        (v) = fminf((v), __int_as_float(_sh));                                \
    } while (0)

// ---- prep: z_e [B][D][L] f32 -> X_bf16 [B*L][D], LDS-transposed ----
__global__ __launch_bounds__(256) void prep_x(const float* __restrict__ ze,
                                              short* __restrict__ xb) {
    __shared__ float t[64][65];
    const int b = blockIdx.x;
    const int l0 = blockIdx.y * 64;
    const int tid = threadIdx.x;
    #pragma unroll
    for (int it = 0; it < 4; ++it) {
        int id = it * 256 + tid;
        int d = id >> 4;
        int lw = (id & 15) * 4;
        const float4 v = *(const float4*)(ze + ((size_t)b * DD + d) * LL + l0 + lw);
        t[d][lw + 0] = v.x; t[d][lw + 1] = v.y; t[d][lw + 2] = v.z; t[d][lw + 3] = v.w;
    }
    __syncthreads();
    #pragma unroll
    for (int it = 0; it < 2; ++it) {
        int id = it * 256 + tid;
        int lr = id >> 3;
        int u = id & 7;
        short8 o;
        #pragma unroll
        for (int e = 0; e < 8; ++e) o[e] = f2bf(t[u * 8 + e][lr]);
        *(short8*)(xb + (size_t)(b * LL + l0 + lr) * DD + u * 8) = o;
    }
}

// ---- prep: nh2[k] = -0.5*||c_k||^2 ----
__global__ __launch_bounds__(256) void prep_nh2(const float* __restrict__ cbf,
                                                float* __restrict__ nh2) {
    int k = blockIdx.x * 256 + threadIdx.x;
    const float4* c4 = (const float4*)(cbf + (size_t)k * DD);
    float s = 0.f;
    #pragma unroll
    for (int i = 0; i < DD / 4; ++i) {
        float4 v = c4[i];
        s += v.x * v.x + v.y * v.y + v.z * v.z + v.w * v.w;
    }
    nh2[k] = -0.5f * s;
}

// ---- Phase A: bf16 MFMA screen. Per (query, 128-code GROUP): max of
//      s = dot(x,c) - 0.5||c||^2, stored fp16 into cmaxG[group][q] ----
__global__ __launch_bounds__(256) void vq_screen(const float* __restrict__ cbf,
                                                 const float* __restrict__ nh2,
                                                 const short* __restrict__ xb,
                                                 __half* __restrict__ cmaxG) {
    __shared__ short cbt[CHUNK * 64];   // 32KB, XOR-swizzled bf16 chunk
    __shared__ float sh2[CHUNK];
    const int tid = threadIdx.x;
    const int lane = tid & 63;
    const int wid = tid >> 6;
    const int kbase = blockIdx.y * CHUNK;
    const int qbase = blockIdx.x * 256 + wid * 64;
    const int r16 = lane & 15, g = lane >> 4;

    #pragma unroll
    for (int it = 0; it < 8; ++it) {
        int id = it * 256 + tid;
        int row = id >> 3;
        int u = id & 7;
        const float4 lo = *(const float4*)(cbf + (size_t)(kbase + row) * 64 + u * 8);
        const float4 hi = *(const float4*)(cbf + (size_t)(kbase + row) * 64 + u * 8 + 4);
        short8 o;
        o[0] = f2bf(lo.x); o[1] = f2bf(lo.y); o[2] = f2bf(lo.z); o[3] = f2bf(lo.w);
        o[4] = f2bf(hi.x); o[5] = f2bf(hi.y); o[6] = f2bf(hi.z); o[7] = f2bf(hi.w);
        *(short8*)(&cbt[row * 64 + ((u ^ (row & 7)) * 8)]) = o;
    }
    sh2[tid] = nh2[kbase + tid];
    __syncthreads();

    short8 a[4][2];
    #pragma unroll
    for (int t = 0; t < 4; ++t)
        #pragma unroll
        for (int ks = 0; ks < 2; ++ks)
            a[t][ks] = *(const short8*)(xb + (size_t)(qbase + t * 16 + r16) * 64 + ks * 32 + g * 8);

    float rm[2][4][4];   // [half][t][j] — static indexing (cs loop unrolled)
    #pragma unroll
    for (int h = 0; h < 2; ++h)
        #pragma unroll
        for (int t = 0; t < 4; ++t)
            #pragma unroll
            for (int j = 0; j < 4; ++j) rm[h][t][j] = -3.4e38f;

    #pragma unroll
    for (int cs = 0; cs < CHUNK / 16; ++cs) {
        const int rowb = cs * 16 + r16;
        const float nh = sh2[rowb];
        const f32x4 ci = {nh, nh, nh, nh};
        const short8 b0 = *(const short8*)(&cbt[rowb * 64 + ((g ^ (rowb & 7)) * 8)]);
        const short8 b1 = *(const short8*)(&cbt[rowb * 64 + (((g + 4) ^ (rowb & 7)) * 8)]);
        #pragma unroll
        for (int t = 0; t < 4; ++t) {
            f32x4 acc = __builtin_amdgcn_mfma_f32_16x16x32_bf16(a[t][0], b0, ci, 0, 0, 0);
            acc = __builtin_amdgcn_mfma_f32_16x16x32_bf16(a[t][1], b1, acc, 0, 0, 0);
            rm[cs >> 3][t][0] = fmaxf(rm[cs >> 3][t][0], acc[0]);
            rm[cs >> 3][t][1] = fmaxf(rm[cs >> 3][t][1], acc[1]);
            rm[cs >> 3][t][2] = fmaxf(rm[cs >> 3][t][2], acc[2]);
            rm[cs >> 3][t][3] = fmaxf(rm[cs >> 3][t][3], acc[3]);
        }
    }

    #pragma unroll
    for (int s = 1; s < 16; s <<= 1)
        #pragma unroll
        for (int h = 0; h < 2; ++h)
            #pragma unroll
            for (int t = 0; t < 4; ++t)
                #pragma unroll
                for (int j = 0; j < 4; ++j)
                    rm[h][t][j] = fmaxf(rm[h][t][j], __shfl_xor(rm[h][t][j], s));

    if (r16 == 0) {   // D layout: query row = (lane>>4)*4 + reg
        #pragma unroll
        for (int h = 0; h < 2; ++h)
            #pragma unroll
            for (int t = 0; t < 4; ++t)
                #pragma unroll
                for (int j = 0; j < 4; ++j)
                    cmaxG[(size_t)(blockIdx.y * 2 + h) * NQ + (qbase + t * 16 + g * 4 + j)] =
                        __float2half(rm[h][t][j]);
    }
}

// ---- Phase B1: per-query threshold + keys init (replaces vq_cand) ----
__global__ __launch_bounds__(256) void vq_thr(const __half* __restrict__ cmaxG,
                                              __half* __restrict__ thr,
                                              u64* __restrict__ keys) {
    int q = blockIdx.x * 256 + threadIdx.x;
    float m = -3.4e38f;
    #pragma unroll
    for (int j = 0; j < NG; ++j)
        m = fmaxf(m, __half2float(cmaxG[(size_t)j * NQ + q]));   // coalesced per j
    thr[q] = __float2half_rd(m - MARGIN);   // round down: admission stays safe
    keys[q] = ~0ULL;
}

// ---- Phase B2: exact fp32 pass. 1 wave = 64 codes (half-group) x 256-q
//      slice; self-admitting via cmaxG/thr; x read uniform from z_e ----
__global__ __launch_bounds__(64) void vq_exact(const float* __restrict__ ze,
                                               const float* __restrict__ cbf,
                                               const float* __restrict__ nh2,
                                               const __half* __restrict__ cmaxG,
                                               const __half* __restrict__ thr,
                                               u64* __restrict__ keys) {
    const int g2 = blockIdx.x;                  // half-group 0..127
    const int slice = blockIdx.y;               // 0..ESL-1
    const int lane = threadIdx.x;
    const int q0 = slice * EQS;
    const int grp = g2 >> 1;

    u64 words[EQS / 64];
    u64 any = 0;
    #pragma unroll
    for (int w = 0; w < EQS / 64; ++w) {        // coalesced fp16 reads + ballot
        int q = q0 + w * 64 + lane;
        float gm = __half2float(cmaxG[(size_t)grp * NQ + q]);
        float th = __half2float(thr[q]);
        u64 mm = __ballot(gm >= th);
        words[w] = mm; any |= mm;
    }
    if (!any) return;                           // cheap exit, no code load

    const int kb = g2 * 64;
    const int k = kb + lane;
    float cdv[64];                              // this lane's code row
    #pragma unroll
    for (int i = 0; i < 16; ++i)
        *(float4*)&cdv[4 * i] = *(const float4*)(cbf + (size_t)k * DD + 4 * i);
    const float nh2k = nh2[k];

    #pragma unroll 1
    for (int w = 0; w < EQS / 64; ++w) {
        u64 sw = words[w];
        while (sw) {
            const int bit = __ffsll((long long)sw) - 1;
            sw &= sw - 1;
            const int qt = q0 + w * 64 + bit;
            const int b = qt >> 11, l = qt & (LL - 1);
            const float* base = ze + (size_t)b * DD * LL + l;   // wave-uniform
            float a0 = 0.f, a1 = 0.f, a2 = 0.f, a3 = 0.f;
            #pragma unroll
            for (int i = 0; i < 16; ++i) {      // 64 uniform dword loads, 4 chains
                float x0 = base[(size_t)(4 * i + 0) * LL];
                float x1 = base[(size_t)(4 * i + 1) * LL];
                float x2 = base[(size_t)(4 * i + 2) * LL];
                float x3 = base[(size_t)(4 * i + 3) * LL];
                a0 = fmaf(x0, cdv[4 * i + 0], a0);
                a1 = fmaf(x1, cdv[4 * i + 1], a1);
                a2 = fmaf(x2, cdv[4 * i + 2], a2);
                a3 = fmaf(x3, cdv[4 * i + 3], a3);
            }
            float val = -(((a0 + a1) + (a2 + a3)) + nh2k);

            float mn = val;                     // DPP wave64 min (VALU only)
            FMIN_DPP(mn, 0x111);   // row_shr:1
            FMIN_DPP(mn, 0x112);   // row_shr:2
            FMIN_DPP(mn, 0x114);   // row_shr:4
            FMIN_DPP(mn, 0x118);   // row_shr:8
            FMIN_DPP(mn, 0x142);   // row_bcast:15
            FMIN_DPP(mn, 0x143);   // row_bcast:31
            const float mnall = __uint_as_float(
                __builtin_amdgcn_readlane(__float_as_uint(mn), 63));

            u64 mk = __ballot(val == mnall);          // lane order = code order
            int srcl = __ffsll((long long)mk) - 1;    // lowest index on ties
            uint32_t uu = __float_as_uint(mnall);
            uint32_t ub = ((int)uu < 0) ? ~uu : (uu | 0x80000000u);
            u64 key = ((u64)ub << 32) | (unsigned)(kb + srcl);
            if (lane == 0) atomicMin(&keys[qt], key);
        }
    }
}

// ---- final: v_q gather + index write (d==0 threads emit indices) ----
__global__ __launch_bounds__(256) void vq_gather(const float* __restrict__ cb,
                                                 const u64* __restrict__ keys,
                                                 float* __restrict__ vq,
                                                 float* __restrict__ oidx) {
    int t = blockIdx.x * 256 + threadIdx.x;
    int l = t & (LL - 1);
    int bd = t >> 11;
    int d = bd & 63;
    int b = bd >> 6;
    int idx = (int)(unsigned)(keys[b * LL + l] & 0x1FFFu);
    vq[t] = cb[idx * DD + d];
    if (d == 0) oidx[b * LL + l] = (float)idx;
}

extern "C" void kernel_launch(void* const* d_in, const int* in_sizes, int n_in,
                              void* d_out, int out_size, void* d_ws, size_t ws_size,
                              hipStream_t stream) {
    const float* ze = (const float*)d_in[0];
    const float* cb = (const float*)d_in[1];
    float* out = (float*)d_out;

    short* xb = (short*)d_out;                                      // [0,4MB)
    __half* cmaxG = (__half*)((char*)d_out + (size_t)NQ * DD * 2);  // [4,8MB)
    __half* thr = (__half*)(out + VQ_SIZE);                         // 64KB of idx region
    float* nh2 = (float*)d_ws;                                      // 32KB
    u64* keys = (u64*)((char*)d_ws + (size_t)KK * 4);               // 256KB
    float* oidx = out + VQ_SIZE;

    dim3 gx(BB, LL / 64);
    prep_x<<<gx, 256, 0, stream>>>(ze, xb);
    prep_nh2<<<KK / 256, 256, 0, stream>>>(cb, nh2);

    dim3 gs(NQ / 256, NCH);
    vq_screen<<<gs, 256, 0, stream>>>(cb, nh2, xb, cmaxG);

    vq_thr<<<NQ / 256, 256, 0, stream>>>(cmaxG, thr, keys);

    dim3 ge(NHG, ESL);
    vq_exact<<<ge, 64, 0, stream>>>(ze, cb, nh2, cmaxG, thr, keys);

    vq_gather<<<VQ_SIZE / 256, 256, 0, stream>>>(cb, keys, out, oidx);
}

// Round 12
// 161.158 us; speedup vs baseline: 1.2605x; 1.1972x over previous
//
#include <hip/hip_runtime.h>
#include <cstdint>

#define BB 16
#define DD 64
#define LL 2048
#define NQ (BB*LL)          // 32768 queries
#define KK 8192             // codebook entries
#define VQ_SIZE (BB*DD*LL)  // 2097152 floats
#define CHUNK 256
#define NCH (KK/CHUNK)      // 32 chunks
#define QSL 256             // query slices per chunk in vq_exact (r9 optimum)
#define QPS (NQ/QSL)        // 128 queries per slice (2 bitmap words)
#define MARGIN 0.75f        // > worst-case 2*eps_bf16 (~0.60) + slack

typedef __attribute__((ext_vector_type(8))) short short8;
typedef __attribute__((ext_vector_type(4))) float f32x4;
typedef unsigned long long u64;

// d_out region reuse:
//   [0, 4MB)  xb bf16 (screen input)      } both dead after vq_cand ->
//   [4, 8MB)  cmaxT [NCH][NQ] f32         }   xf f32 [NQ][64] (8 MB exactly)
//   [8MB, +128KB) indices region: qmask[NCH][NQ/64] u64 (exactly 128 KB),
//                 overwritten with float indices by vq_gather at the end.
// d_ws: nh2[KK] f32 (32KB) + keys[NQ] u64 (256KB) = 288KB (proven available)

static __device__ inline short f2bf(float f) {   // RNE f32 -> bf16
    uint32_t u = __float_as_uint(f);
    uint32_t r = (u + 0x7FFFu + ((u >> 16) & 1u)) >> 16;
    return (short)r;
}

// DPP wave64 min-reduce step (pure VALU; correctness proven rounds 10-11)
#define FMIN_DPP(v, ctrl)                                                     \
    do {                                                                      \
        int _vi = __float_as_int(v);                                          \
        int _sh = __builtin_amdgcn_update_dpp(_vi, _vi, (ctrl), 0xf, 0xf, false); \
        (v) = fminf((v), __int_as_float(_sh));                                \
    } while (0)

// ---- prep: z_e [B][D][L] f32 -> X_bf16 [B*L][D], LDS-transposed ----
__global__ __launch_bounds__(256) void prep_x(const float* __restrict__ ze,
                                              short* __restrict__ xb) {
    __shared__ float t[64][65];
    const int b = blockIdx.x;
    const int l0 = blockIdx.y * 64;
    const int tid = threadIdx.x;
    #pragma unroll
    for (int it = 0; it < 4; ++it) {
        int id = it * 256 + tid;
        int d = id >> 4;
        int lw = (id & 15) * 4;
        const float4 v = *(const float4*)(ze + ((size_t)b * DD + d) * LL + l0 + lw);
        t[d][lw + 0] = v.x; t[d][lw + 1] = v.y; t[d][lw + 2] = v.z; t[d][lw + 3] = v.w;
    }
    __syncthreads();
    #pragma unroll
    for (int it = 0; it < 2; ++it) {
        int id = it * 256 + tid;
        int lr = id >> 3;
        int u = id & 7;
        short8 o;
        #pragma unroll
        for (int e = 0; e < 8; ++e) o[e] = f2bf(t[u * 8 + e][lr]);
        *(short8*)(xb + (size_t)(b * LL + l0 + lr) * DD + u * 8) = o;
    }
}

// ---- prep: z_e -> xf f32 [B*L][D] (contiguous rows for exact pass) ----
__global__ __launch_bounds__(256) void prep_xf(const float* __restrict__ ze,
                                               float* __restrict__ xf) {
    __shared__ float t[64][65];
    const int b = blockIdx.x;
    const int l0 = blockIdx.y * 64;
    const int tid = threadIdx.x;
    #pragma unroll
    for (int it = 0; it < 4; ++it) {
        int id = it * 256 + tid;
        int d = id >> 4;
        int lw = (id & 15) * 4;
        const float4 v = *(const float4*)(ze + ((size_t)b * DD + d) * LL + l0 + lw);
        t[d][lw + 0] = v.x; t[d][lw + 1] = v.y; t[d][lw + 2] = v.z; t[d][lw + 3] = v.w;
    }
    __syncthreads();
    #pragma unroll
    for (int it = 0; it < 4; ++it) {
        int id = it * 256 + tid;        // row*16 + u
        int row = id >> 4;
        int u = id & 15;
        float4 o = make_float4(t[4 * u + 0][row], t[4 * u + 1][row],
                               t[4 * u + 2][row], t[4 * u + 3][row]);
        *(float4*)(xf + (size_t)(b * LL + l0 + row) * DD + u * 4) = o;
    }
}

// ---- prep: nh2[k] = -0.5*||c_k||^2 ----
__global__ __launch_bounds__(256) void prep_nh2(const float* __restrict__ cbf,
                                                float* __restrict__ nh2) {
    int k = blockIdx.x * 256 + threadIdx.x;
    const float4* c4 = (const float4*)(cbf + (size_t)k * DD);
    float s = 0.f;
    #pragma unroll
    for (int i = 0; i < DD / 4; ++i) {
        float4 v = c4[i];
        s += v.x * v.x + v.y * v.y + v.z * v.z + v.w * v.w;
    }
    nh2[k] = -0.5f * s;
}

// ---- Phase A: bf16 MFMA screen -> cmaxT[ch][q] = max_k s(q,k) over chunk ----
__global__ __launch_bounds__(256) void vq_screen(const float* __restrict__ cbf,
                                                 const float* __restrict__ nh2,
                                                 const short* __restrict__ xb,
                                                 float* __restrict__ cmaxT) {
    __shared__ short cbt[CHUNK * 64];   // 32KB, XOR-swizzled bf16 chunk
    __shared__ float sh2[CHUNK];
    const int tid = threadIdx.x;
    const int lane = tid & 63;
    const int wid = tid >> 6;
    const int kbase = blockIdx.y * CHUNK;
    const int qbase = blockIdx.x * 256 + wid * 64;
    const int r16 = lane & 15, g = lane >> 4;

    #pragma unroll
    for (int it = 0; it < 8; ++it) {
        int id = it * 256 + tid;
        int row = id >> 3;
        int u = id & 7;
        const float4 lo = *(const float4*)(cbf + (size_t)(kbase + row) * 64 + u * 8);
        const float4 hi = *(const float4*)(cbf + (size_t)(kbase + row) * 64 + u * 8 + 4);
        short8 o;
        o[0] = f2bf(lo.x); o[1] = f2bf(lo.y); o[2] = f2bf(lo.z); o[3] = f2bf(lo.w);
        o[4] = f2bf(hi.x); o[5] = f2bf(hi.y); o[6] = f2bf(hi.z); o[7] = f2bf(hi.w);
        *(short8*)(&cbt[row * 64 + ((u ^ (row & 7)) * 8)]) = o;
    }
    sh2[tid] = nh2[kbase + tid];
    __syncthreads();

    short8 a[4][2];
    #pragma unroll
    for (int t = 0; t < 4; ++t)
        #pragma unroll
        for (int ks = 0; ks < 2; ++ks)
            a[t][ks] = *(const short8*)(xb + (size_t)(qbase + t * 16 + r16) * 64 + ks * 32 + g * 8);

    float rm[4][4];
    #pragma unroll
    for (int t = 0; t < 4; ++t)
        #pragma unroll
        for (int j = 0; j < 4; ++j) rm[t][j] = -3.4e38f;

    for (int cs = 0; cs < CHUNK / 16; ++cs) {
        const int rowb = cs * 16 + r16;
        const float nh = sh2[rowb];
        const f32x4 ci = {nh, nh, nh, nh};
        const short8 b0 = *(const short8*)(&cbt[rowb * 64 + ((g ^ (rowb & 7)) * 8)]);
        const short8 b1 = *(const short8*)(&cbt[rowb * 64 + (((g + 4) ^ (rowb & 7)) * 8)]);
        #pragma unroll
        for (int t = 0; t < 4; ++t) {
            f32x4 acc = __builtin_amdgcn_mfma_f32_16x16x32_bf16(a[t][0], b0, ci, 0, 0, 0);
            acc = __builtin_amdgcn_mfma_f32_16x16x32_bf16(a[t][1], b1, acc, 0, 0, 0);
            rm[t][0] = fmaxf(rm[t][0], acc[0]);
            rm[t][1] = fmaxf(rm[t][1], acc[1]);
            rm[t][2] = fmaxf(rm[t][2], acc[2]);
            rm[t][3] = fmaxf(rm[t][3], acc[3]);
        }
    }

    #pragma unroll
    for (int s = 1; s < 16; s <<= 1)
        #pragma unroll
        for (int t = 0; t < 4; ++t)
            #pragma unroll
            for (int j = 0; j < 4; ++j)
                rm[t][j] = fmaxf(rm[t][j], __shfl_xor(rm[t][j], s));

    if (r16 == 0) {   // transposed write: cmaxT[ch][q]
        #pragma unroll
        for (int t = 0; t < 4; ++t)
            #pragma unroll
            for (int j = 0; j < 4; ++j)
                cmaxT[(size_t)blockIdx.y * NQ + (qbase + t * 16 + g * 4 + j)] = rm[t][j];
    }
}

// ---- Phase B1: candidate bitmap via ballot (atomic-free, deterministic) ----
__global__ __launch_bounds__(256) void vq_cand(const float* __restrict__ cmaxT,
                                               u64* __restrict__ qmask,
                                               u64* __restrict__ keys) {
    const int tid = threadIdx.x;
    const int lane = tid & 63;
    const int q = blockIdx.x * 256 + tid;
    const int qword = q >> 6;   // wave-uniform
    float v[NCH];
    float m = -3.4e38f;
    #pragma unroll
    for (int j = 0; j < NCH; ++j) {
        v[j] = cmaxT[(size_t)j * NQ + q];
        m = fmaxf(m, v[j]);
    }
    keys[q] = ~0ULL;
    const float thr = m - MARGIN;
    #pragma unroll
    for (int j = 0; j < NCH; ++j) {
        u64 mm = __ballot(v[j] >= thr);
        if (lane == 0) qmask[(size_t)j * (NQ / 64) + qword] = mm;
    }
}

// ---- Phase B2: exact fp32 pass. lane=code; single-query visits;
//      x via contiguous float4 loads from xf; DPP min-reduce ----
__global__ __launch_bounds__(256) void vq_exact(const float* __restrict__ xf,
                                                const float* __restrict__ cbf,
                                                const float* __restrict__ nh2,
                                                const u64* __restrict__ qmask,
                                                u64* __restrict__ keys) {
    const int ch = blockIdx.x;
    const int slice = blockIdx.y;                 // 0..QSL-1
    const int lane = threadIdx.x & 63;
    const int wid = threadIdx.x >> 6;
    const int kb = ch * CHUNK + wid * 64;
    const int k = kb + lane;

    const u64* wm = qmask + (size_t)ch * (NQ / 64) + slice * (QPS / 64);
    u64 words[QPS / 64];
    u64 any = 0;
    #pragma unroll
    for (int w = 0; w < QPS / 64; ++w) {
        u64 x = wm[w];
        uint32_t lo = __builtin_amdgcn_readfirstlane((uint32_t)x);
        uint32_t hi = __builtin_amdgcn_readfirstlane((uint32_t)(x >> 32));
        words[w] = ((u64)hi << 32) | lo;          // SALU-resident
        any |= words[w];
    }
    if (!any) return;                             // skip code load entirely

    float cdv[64];                                // this lane's code row
    #pragma unroll
    for (int i = 0; i < 16; ++i)
        *(float4*)&cdv[4 * i] = *(const float4*)(cbf + (size_t)k * DD + 4 * i);
    const float nh2k = nh2[k];

    #pragma unroll 1
    for (int w = 0; w < QPS / 64; ++w) {
        u64 sw = words[w];
        while (sw) {
            const int bit = __ffsll((long long)sw) - 1;
            sw &= sw - 1;
            const int q = slice * QPS + w * 64 + bit;
            const float4* xr4 = (const float4*)(xf + (size_t)q * DD);
            float4 xv[16];                         // 16 independent loads in flight
            #pragma unroll
            for (int i = 0; i < 16; ++i) xv[i] = xr4[i];

            float a0 = 0.f, a1 = 0.f, a2 = 0.f, a3 = 0.f;
            #pragma unroll
            for (int i = 0; i < 16; ++i) {         // 4 independent fma chains
                a0 = fmaf(xv[i].x, cdv[4 * i + 0], a0);
                a1 = fmaf(xv[i].y, cdv[4 * i + 1], a1);
                a2 = fmaf(xv[i].z, cdv[4 * i + 2], a2);
                a3 = fmaf(xv[i].w, cdv[4 * i + 3], a3);
            }
            float val = -(((a0 + a1) + (a2 + a3)) + nh2k);

            float mn = val;                        // DPP wave64 min (VALU only)
            FMIN_DPP(mn, 0x111);   // row_shr:1
            FMIN_DPP(mn, 0x112);   // row_shr:2
            FMIN_DPP(mn, 0x114);   // row_shr:4
            FMIN_DPP(mn, 0x118);   // row_shr:8
            FMIN_DPP(mn, 0x142);   // row_bcast:15
            FMIN_DPP(mn, 0x143);   // row_bcast:31
            const float mnall = __uint_as_float(
                __builtin_amdgcn_readlane(__float_as_uint(mn), 63));

            u64 mk = __ballot(val == mnall);       // lane order = code order
            int srcl = __ffsll((long long)mk) - 1; // lowest index on ties
            uint32_t uu = __float_as_uint(mnall);
            uint32_t ub = ((int)uu < 0) ? ~uu : (uu | 0x80000000u);
            u64 key = ((u64)ub << 32) | (unsigned)(kb + srcl);
            if (lane == 0) atomicMin(&keys[q], key);
        }
    }
}

// ---- final: v_q gather + index write (d==0 threads emit indices) ----
__global__ __launch_bounds__(256) void vq_gather(const float* __restrict__ cb,
                                                 const u64* __restrict__ keys,
                                                 float* __restrict__ vq,
                                                 float* __restrict__ oidx) {
    int t = blockIdx.x * 256 + threadIdx.x;
    int l = t & (LL - 1);
    int bd = t >> 11;
    int d = bd & 63;
    int b = bd >> 6;
    int idx = (int)(unsigned)(keys[b * LL + l] & 0x1FFFu);
    vq[t] = cb[idx * DD + d];
    if (d == 0) oidx[b * LL + l] = (float)idx;
}

extern "C" void kernel_launch(void* const* d_in, const int* in_sizes, int n_in,
                              void* d_out, int out_size, void* d_ws, size_t ws_size,
                              hipStream_t stream) {
    const float* ze = (const float*)d_in[0];
    const float* cb = (const float*)d_in[1];
    float* out = (float*)d_out;

    short* xb = (short*)d_out;                                    // [0,4MB)
    float* cmaxT = (float*)((char*)d_out + (size_t)NQ * DD * 2);  // [4,8MB)
    float* xf = (float*)d_out;                                    // [0,8MB) after cand
    u64* qmask = (u64*)(out + VQ_SIZE);                           // 128KB indices region
    float* nh2 = (float*)d_ws;                                    // 32KB
    u64* keys = (u64*)((char*)d_ws + (size_t)KK * 4);             // 256KB
    float* oidx = out + VQ_SIZE;

    dim3 gx(BB, LL / 64);
    prep_x<<<gx, 256, 0, stream>>>(ze, xb);
    prep_nh2<<<KK / 256, 256, 0, stream>>>(cb, nh2);

    dim3 gs(NQ / 256, NCH);
    vq_screen<<<gs, 256, 0, stream>>>(cb, nh2, xb, cmaxT);

    vq_cand<<<NQ / 256, 256, 0, stream>>>(cmaxT, qmask, keys);

    prep_xf<<<gx, 256, 0, stream>>>(ze, xf);   // overwrites xb+cmaxT (both dead)

    dim3 ge(NCH, QSL);
    vq_exact<<<ge, 256, 0, stream>>>(xf, cb, nh2, qmask, keys);

    vq_gather<<<VQ_SIZE / 256, 256, 0, stream>>>(cb, keys, out, oidx);
}